// Round 1
// baseline (9.678 us; speedup 1.0000x reference)
//
#include <hip/hip_runtime.h>

#define N_QUBITS 16
#define BSZ 256

// out[b,w] = cos(x[b,w] + thetas[w])
// Derivation: all gates are RX on distinct wires from |0..0> -> product state.
// RX(x)RX(theta) = RX(x+theta); <Z> of RX(phi)|0> is cos(phi).
__global__ void qc_rx_expz_kernel(const float* __restrict__ x,
                                  const float* __restrict__ thetas,
                                  float* __restrict__ out) {
    __shared__ float th[N_QUBITS];
    if (threadIdx.x < N_QUBITS) th[threadIdx.x] = thetas[threadIdx.x];
    __syncthreads();

    int i = blockIdx.x * blockDim.x + threadIdx.x;  // flat index into [BSZ, N_QUBITS]
    if (i < BSZ * N_QUBITS) {
        int w = i & (N_QUBITS - 1);
        out[i] = cosf(x[i] + th[w]);
    }
}

extern "C" void kernel_launch(void* const* d_in, const int* in_sizes, int n_in,
                              void* d_out, int out_size, void* d_ws, size_t ws_size,
                              hipStream_t stream) {
    const float* x = (const float*)d_in[0];       // [BSZ, N_QUBITS]
    const float* thetas = (const float*)d_in[1];  // [N_QUBITS]
    float* out = (float*)d_out;                   // [BSZ, N_QUBITS]

    const int total = BSZ * N_QUBITS;  // 4096
    const int block = 256;
    const int grid = (total + block - 1) / block;  // 16
    qc_rx_expz_kernel<<<grid, block, 0, stream>>>(x, thetas, out);
}